// Round 1
// baseline (774.425 us; speedup 1.0000x reference)
//
#include <hip/hip_runtime.h>
#include <stdint.h>

#define N_TOK 16384
#define DIM   1024
#define NEXP  8
#define FF    2048
#define CAP   2560
#define NSLOT (NEXP*CAP)   // 20480

using f32x4  = __attribute__((ext_vector_type(4))) float;
using bf16x8 = __attribute__((ext_vector_type(8))) short;

__device__ __forceinline__ unsigned short f2bf(float f){
  union { float f; unsigned u; } c; c.f = f;
  unsigned u = c.u + 0x7FFFu + ((c.u >> 16) & 1u);   // RNE
  return (unsigned short)(u >> 16);
}

__device__ __forceinline__ void gld16(const unsigned short* g, unsigned short* l){
  __builtin_amdgcn_global_load_lds((__attribute__((address_space(1))) void*)(void*)g,
                                   (__attribute__((address_space(3))) void*)l,
                                   16, 0, 0);
}

// ---------------- router: fp64 logits/softmax for ordering robustness ----------------
__global__ __launch_bounds__(256) void k_router(
    const float* __restrict__ x, const float* __restrict__ gate_w,
    float* __restrict__ probs, int* __restrict__ topidx, float* __restrict__ topw)
{
  __shared__ float gwT[NEXP][DIM];   // 32 KB, transposed for conflict-free reads
  int tid = threadIdx.x;
  for (int i = tid; i < DIM*NEXP; i += 256) gwT[i & 7][i >> 3] = gate_w[i];
  __syncthreads();
  int wave = tid >> 6, lane = tid & 63;
  int t = blockIdx.x * 4 + wave;
  const float* xr = x + (size_t)t * DIM;
  double acc[NEXP];
  #pragma unroll
  for (int e = 0; e < NEXP; e++) acc[e] = 0.0;
  for (int j = 0; j < DIM/64; j++){
    double xv = (double)xr[lane + 64*j];
    #pragma unroll
    for (int e = 0; e < NEXP; e++) acc[e] += xv * (double)gwT[e][lane + 64*j];
  }
  #pragma unroll
  for (int off = 32; off >= 1; off >>= 1){
    #pragma unroll
    for (int e = 0; e < NEXP; e++) acc[e] += __shfl_xor(acc[e], off, 64);
  }
  if (lane == 0){
    double m = acc[0];
    #pragma unroll
    for (int e = 1; e < NEXP; e++) m = fmax(m, acc[e]);
    double p[NEXP], Z = 0.0;
    #pragma unroll
    for (int e = 0; e < NEXP; e++){ p[e] = exp(acc[e] - m); Z += p[e]; }
    double invZ = 1.0 / Z;
    #pragma unroll
    for (int e = 0; e < NEXP; e++){ p[e] *= invZ; probs[t*NEXP + e] = (float)p[e]; }
    int i0 = 0; double p0 = p[0];
    #pragma unroll
    for (int e = 1; e < NEXP; e++) if (p[e] > p0){ p0 = p[e]; i0 = e; }
    int i1 = (i0 == 0) ? 1 : 0; double p1 = p[i1];
    #pragma unroll
    for (int e = 0; e < NEXP; e++) if (e != i0 && p[e] > p1){ p1 = p[e]; i1 = e; }
    double s = p0 + p1;
    topidx[t*2+0] = i0; topidx[t*2+1] = i1;
    topw [t*2+0] = (float)(p0/s); topw[t*2+1] = (float)(p1/s);
  }
}

// ---------------- ordered capacity scan: exact reference cumsum semantics ----------------
__global__ __launch_bounds__(1024) void k_scan(
    const int* __restrict__ topidx, const float* __restrict__ topw,
    int* __restrict__ slot_token, float* __restrict__ slot_w,
    int* __restrict__ counts_total)
{
  __shared__ int sc[1024][NEXP];   // 32 KB
  const int t = threadIdx.x;
  const int base_i = t * 32;       // 32768 entries / 1024 threads
  int ids[32];
  #pragma unroll
  for (int j = 0; j < 32; j++) ids[j] = topidx[base_i + j];
  int b[NEXP];
  #pragma unroll
  for (int e = 0; e < NEXP; e++) b[e] = 0;
  #pragma unroll
  for (int j = 0; j < 32; j++){
    #pragma unroll
    for (int e = 0; e < NEXP; e++) if (ids[j] == e) b[e]++;
  }
  #pragma unroll
  for (int e = 0; e < NEXP; e++) sc[t][e] = b[e];
  __syncthreads();
  for (int off = 1; off < 1024; off <<= 1){
    int tmp[NEXP];
    #pragma unroll
    for (int e = 0; e < NEXP; e++) tmp[e] = (t >= off) ? sc[t-off][e] : 0;
    __syncthreads();
    #pragma unroll
    for (int e = 0; e < NEXP; e++) sc[t][e] += tmp[e];
    __syncthreads();
  }
  int myb[NEXP];
  #pragma unroll
  for (int e = 0; e < NEXP; e++) myb[e] = sc[t][e] - b[e];  // exclusive base
  if (t == 1023){
    #pragma unroll
    for (int e = 0; e < NEXP; e++) counts_total[e] = sc[1023][e];
  }
  #pragma unroll
  for (int j = 0; j < 32; j++){
    #pragma unroll
    for (int e = 0; e < NEXP; e++){
      if (ids[j] == e){
        int r = myb[e]; myb[e] = r + 1;
        if (r < CAP){
          int s = e*CAP + r;
          slot_token[s] = (base_i + j) >> 1;
          slot_w[s]     = topw[base_i + j];
        }
      }
    }
  }
}

// ---------------- transpose + fp32->bf16 cast: [R][C] f32 -> [C][R] bf16 ----------------
__global__ __launch_bounds__(256) void k_transpose_cast(
    const float* __restrict__ in, unsigned short* __restrict__ out, int R, int C)
{
  __shared__ float tile[64][65];
  const int e  = blockIdx.z;
  const float* ine = in + (size_t)e * R * C;
  unsigned short* oute = out + (size_t)e * R * C;
  const int c0 = blockIdx.x * 64, r0 = blockIdx.y * 64;
  const int tx = threadIdx.x & 63, ty = threadIdx.x >> 6;
  #pragma unroll
  for (int i = 0; i < 16; i++){
    int r = ty*16 + i;
    tile[r][tx] = ine[(size_t)(r0 + r) * C + c0 + tx];
  }
  __syncthreads();
  #pragma unroll
  for (int i = 0; i < 16; i++){
    int c = ty*16 + i;
    oute[(size_t)(c0 + c) * R + r0 + tx] = f2bf(tile[tx][c]);
  }
}

// ---------------- gather x rows into dispatched bf16 (zeros for empty slots) ----------------
__global__ __launch_bounds__(256) void k_gather(
    const float* __restrict__ x, const int* __restrict__ slot_token,
    unsigned short* __restrict__ disp)
{
  const int s = blockIdx.x;
  const int t = slot_token[s];
  const int tid = threadIdx.x;
  unsigned long long pk = 0ull;
  if (t >= 0){
    float4 v = *(const float4*)(x + (size_t)t*DIM + tid*4);
    pk =  (unsigned long long)f2bf(v.x)
       | ((unsigned long long)f2bf(v.y) << 16)
       | ((unsigned long long)f2bf(v.z) << 32)
       | ((unsigned long long)f2bf(v.w) << 48);
  }
  *(unsigned long long*)(disp + (size_t)s*DIM + tid*4) = pk;
}

// ---------------- GEMM staging: 128 rows x 64 cols bf16 tile via global_load_lds ----------------
template<int ROW_STRIDE>
__device__ __forceinline__ void stage_tile(const unsigned short* gbase, unsigned short* lds,
                                           int wave, int lane, int k0){
  const int crow = lane >> 3;    // 0..7
  const int ccol = lane & 7;     // *8 bf16 = 16B
  #pragma unroll
  for (int j = 0; j < 4; j++){
    int row = j*32 + wave*8;
    gld16(gbase + (size_t)(row + crow)*ROW_STRIDE + k0 + ccol*8,
          lds + row*64);         // wave-uniform LDS base, lane*16B implicit
  }
}

// ---------------- GEMM1: dispatched @ {w_gate,w_up} fused SiLU -> hidden (bf16) ----------------
__global__ __launch_bounds__(256) void k_gemm1(
    const unsigned short* __restrict__ disp, const unsigned short* __restrict__ wgT,
    const unsigned short* __restrict__ wuT, unsigned short* __restrict__ hidden)
{
  __shared__ unsigned short lA[128*64], lBg[128*64], lBu[128*64];  // 48 KB
  const int e  = blockIdx.y;
  const int mt = blockIdx.x % 20;
  const int nt = blockIdx.x / 20;     // 0..15
  const int m0 = mt*128, n0 = nt*128;
  const unsigned short* Ab = disp + ((size_t)e*CAP + m0) * DIM;
  const unsigned short* Bg = wgT  + ((size_t)e*FF  + n0) * DIM;
  const unsigned short* Bu = wuT  + ((size_t)e*FF  + n0) * DIM;
  const int tid = threadIdx.x, wave = tid >> 6, lane = tid & 63;
  const int wr = wave >> 1, wc = wave & 1;
  const f32x4 zero = {0.f, 0.f, 0.f, 0.f};
  f32x4 accG[4][4], accU[4][4];
  #pragma unroll
  for (int i = 0; i < 4; i++)
    #pragma unroll
    for (int j = 0; j < 4; j++){ accG[i][j] = zero; accU[i][j] = zero; }

  stage_tile<DIM>(Ab, lA,  wave, lane, 0);
  stage_tile<DIM>(Bg, lBg, wave, lane, 0);
  stage_tile<DIM>(Bu, lBu, wave, lane, 0);
  for (int kt = 0; kt < DIM/64; kt++){
    __syncthreads();   // drains vmcnt: staged tile visible
    #pragma unroll
    for (int ks = 0; ks < 2; ks++){
      const int kc = ks*32 + (lane >> 4)*8;
      bf16x8 a[4], bg[4], bu[4];
      #pragma unroll
      for (int q = 0; q < 4; q++){
        a [q] = *(const bf16x8*)&lA [(wr*64 + q*16 + (lane & 15))*64 + kc];
        bg[q] = *(const bf16x8*)&lBg[(wc*64 + q*16 + (lane & 15))*64 + kc];
        bu[q] = *(const bf16x8*)&lBu[(wc*64 + q*16 + (lane & 15))*64 + kc];
      }
      #pragma unroll
      for (int i = 0; i < 4; i++)
        #pragma unroll
        for (int j = 0; j < 4; j++){
          accG[i][j] = __builtin_amdgcn_mfma_f32_16x16x32_bf16(a[i], bg[j], accG[i][j], 0, 0, 0);
          accU[i][j] = __builtin_amdgcn_mfma_f32_16x16x32_bf16(a[i], bu[j], accU[i][j], 0, 0, 0);
        }
    }
    __syncthreads();   // all reads done before restage
    if (kt + 1 < DIM/64){
      stage_tile<DIM>(Ab, lA,  wave, lane, (kt+1)*64);
      stage_tile<DIM>(Bg, lBg, wave, lane, (kt+1)*64);
      stage_tile<DIM>(Bu, lBu, wave, lane, (kt+1)*64);
    }
  }
  unsigned short* Hb = hidden + ((size_t)e*CAP + m0)*FF + n0;
  #pragma unroll
  for (int i = 0; i < 4; i++)
    #pragma unroll
    for (int j = 0; j < 4; j++)
      #pragma unroll
      for (int q = 0; q < 4; q++){
        int r = wr*64 + i*16 + (lane >> 4)*4 + q;
        int c = wc*64 + j*16 + (lane & 15);
        float g = accG[i][j][q], u = accU[i][j][q];
        float h = g / (1.f + __expf(-g)) * u;   // silu(g)*u
        Hb[(size_t)r*FF + c] = f2bf(h);
      }
}

// ---------------- GEMM2: hidden @ w_down, scaled-atomic combine into out ----------------
__global__ __launch_bounds__(256) void k_gemm2(
    const unsigned short* __restrict__ hidden, const unsigned short* __restrict__ wdT,
    const int* __restrict__ slot_token, const float* __restrict__ slot_w,
    float* __restrict__ out)
{
  __shared__ unsigned short lA[128*64], lB[128*64];  // 32 KB
  const int e  = blockIdx.y;
  const int mt = blockIdx.x % 20;
  const int nt = blockIdx.x / 20;    // 0..7
  const int m0 = mt*128, n0 = nt*128;
  const unsigned short* Ab = hidden + ((size_t)e*CAP + m0) * FF;
  const unsigned short* Bb = wdT    + ((size_t)e*DIM + n0) * FF;
  const int tid = threadIdx.x, wave = tid >> 6, lane = tid & 63;
  const int wr = wave >> 1, wc = wave & 1;
  const f32x4 zero = {0.f, 0.f, 0.f, 0.f};
  f32x4 acc[4][4];
  #pragma unroll
  for (int i = 0; i < 4; i++)
    #pragma unroll
    for (int j = 0; j < 4; j++) acc[i][j] = zero;

  stage_tile<FF>(Ab, lA, wave, lane, 0);
  stage_tile<FF>(Bb, lB, wave, lane, 0);
  for (int kt = 0; kt < FF/64; kt++){
    __syncthreads();
    #pragma unroll
    for (int ks = 0; ks < 2; ks++){
      const int kc = ks*32 + (lane >> 4)*8;
      bf16x8 a[4], b[4];
      #pragma unroll
      for (int q = 0; q < 4; q++){
        a[q] = *(const bf16x8*)&lA[(wr*64 + q*16 + (lane & 15))*64 + kc];
        b[q] = *(const bf16x8*)&lB[(wc*64 + q*16 + (lane & 15))*64 + kc];
      }
      #pragma unroll
      for (int i = 0; i < 4; i++)
        #pragma unroll
        for (int j = 0; j < 4; j++)
          acc[i][j] = __builtin_amdgcn_mfma_f32_16x16x32_bf16(a[i], b[j], acc[i][j], 0, 0, 0);
    }
    __syncthreads();
    if (kt + 1 < FF/64){
      stage_tile<FF>(Ab, lA, wave, lane, (kt+1)*64);
      stage_tile<FF>(Bb, lB, wave, lane, (kt+1)*64);
    }
  }
  const int slotbase = e*CAP + m0;
  #pragma unroll
  for (int i = 0; i < 4; i++)
    #pragma unroll
    for (int q = 0; q < 4; q++){
      int r = wr*64 + i*16 + (lane >> 4)*4 + q;
      int s = slotbase + r;
      int t = slot_token[s];
      if (t < 0) continue;
      float w = slot_w[s];
      float* orow = out + (size_t)t*DIM + n0 + wc*64;
      #pragma unroll
      for (int j = 0; j < 4; j++)
        atomicAdd(&orow[j*16 + (lane & 15)], w * acc[i][j][q]);
    }
}

// ---------------- aux loss ----------------
__global__ __launch_bounds__(256) void k_aux(
    const float* __restrict__ probs, const int* __restrict__ counts_total,
    float* __restrict__ aux_out)
{
  const int tid = threadIdx.x;
  float pe[NEXP];
  #pragma unroll
  for (int e = 0; e < NEXP; e++) pe[e] = 0.f;
  for (int i = tid; i < N_TOK; i += 256){
    #pragma unroll
    for (int e = 0; e < NEXP; e++) pe[e] += probs[i*NEXP + e];
  }
  #pragma unroll
  for (int off = 32; off >= 1; off >>= 1){
    #pragma unroll
    for (int e = 0; e < NEXP; e++) pe[e] += __shfl_xor(pe[e], off, 64);
  }
  __shared__ float part[4][NEXP];
  const int wave = tid >> 6, lane = tid & 63;
  if (lane == 0){
    #pragma unroll
    for (int e = 0; e < NEXP; e++) part[wave][e] = pe[e];
  }
  __syncthreads();
  if (tid == 0){
    float aux = 0.f;
    for (int e = 0; e < NEXP; e++){
      float P = (part[0][e] + part[1][e] + part[2][e] + part[3][e]) / (float)N_TOK;
      float f = (float)counts_total[e] / ((float)(N_TOK*2) + 1e-9f);
      aux += f * P;
    }
    aux_out[0] = (float)NEXP * aux * 0.01f;
  }
}

extern "C" void kernel_launch(void* const* d_in, const int* in_sizes, int n_in,
                              void* d_out, int out_size, void* d_ws, size_t ws_size,
                              hipStream_t stream)
{
  const float* x      = (const float*)d_in[0];
  const float* gate_w = (const float*)d_in[1];
  const float* w_gate = (const float*)d_in[2];
  const float* w_up   = (const float*)d_in[3];
  const float* w_down = (const float*)d_in[4];
  float* out = (float*)d_out;

  uint8_t* ws = (uint8_t*)d_ws;
  float* probs        = (float*)ws;            ws += (size_t)N_TOK*NEXP*4;       // 524288
  int*   topidx       = (int*)ws;              ws += (size_t)N_TOK*2*4;          // 131072
  float* topw         = (float*)ws;            ws += (size_t)N_TOK*2*4;          // 131072
  int*   slot_token   = (int*)ws;              ws += (size_t)NSLOT*4;            // 81920
  float* slot_w       = (float*)ws;            ws += (size_t)NSLOT*4;            // 81920
  int*   counts_total = (int*)ws;              ws += 256;
  unsigned short* disp   = (unsigned short*)ws; ws += (size_t)NSLOT*DIM*2;       // 41.9 MB
  unsigned short* hidden = (unsigned short*)ws; ws += (size_t)NSLOT*FF*2;        // 83.9 MB
  unsigned short* wgT    = (unsigned short*)ws; ws += (size_t)NEXP*DIM*FF*2;     // 33.6 MB
  unsigned short* wuT    = (unsigned short*)ws; ws += (size_t)NEXP*DIM*FF*2;
  unsigned short* wdT    = (unsigned short*)ws; ws += (size_t)NEXP*DIM*FF*2;
  size_t need = (size_t)(ws - (uint8_t*)d_ws);
  if (ws_size < need) return;  // leaves poison -> distinguishable failure signature

  hipMemsetAsync(d_out, 0, (size_t)out_size * sizeof(float), stream);
  hipMemsetAsync(slot_token, 0xFF, (size_t)NSLOT * sizeof(int), stream);

  k_router<<<N_TOK/4, 256, 0, stream>>>(x, gate_w, probs, topidx, topw);
  k_scan<<<1, 1024, 0, stream>>>(topidx, topw, slot_token, slot_w, counts_total);
  // w_gate [E][D][F] -> wgT [E][F][D]; w_up same; w_down [E][F][D] -> wdT [E][D][F]
  k_transpose_cast<<<dim3(FF/64, DIM/64, NEXP), 256, 0, stream>>>(w_gate, wgT, DIM, FF);
  k_transpose_cast<<<dim3(FF/64, DIM/64, NEXP), 256, 0, stream>>>(w_up,   wuT, DIM, FF);
  k_transpose_cast<<<dim3(DIM/64, FF/64, NEXP), 256, 0, stream>>>(w_down, wdT, FF, DIM);
  k_gather<<<NSLOT, 256, 0, stream>>>(x, slot_token, disp);
  k_gemm1<<<dim3(20*16, NEXP), 256, 0, stream>>>(disp, wgT, wuT, hidden);
  k_gemm2<<<dim3(20*8,  NEXP), 256, 0, stream>>>(hidden, wdT, slot_token, slot_w, out);
  k_aux<<<1, 256, 0, stream>>>(probs, counts_total, out + (size_t)N_TOK*DIM);
}

// Round 2
// 531.557 us; speedup vs baseline: 1.4569x; 1.4569x over previous
//
#include <hip/hip_runtime.h>
#include <stdint.h>

#define N_TOK 16384
#define DIM   1024
#define NEXP  8
#define FF    2048
#define CAP   2560
#define NSLOT (NEXP*CAP)   // 20480

using f32x4  = __attribute__((ext_vector_type(4))) float;
using bf16x8 = __attribute__((ext_vector_type(8))) short;

__device__ __forceinline__ unsigned short f2bf(float f){
  union { float f; unsigned u; } c; c.f = f;
  unsigned u = c.u + 0x7FFFu + ((c.u >> 16) & 1u);   // RNE
  return (unsigned short)(u >> 16);
}
__device__ __forceinline__ float bf2f(unsigned short h){
  union { unsigned u; float f; } c; c.u = ((unsigned)h) << 16; return c.f;
}

__device__ __forceinline__ void gld16(const unsigned short* g, unsigned short* l){
  __builtin_amdgcn_global_load_lds((__attribute__((address_space(1))) void*)(void*)g,
                                   (__attribute__((address_space(3))) void*)l,
                                   16, 0, 0);
}

#define SBAR __builtin_amdgcn_sched_barrier(0)
#define HBAR __builtin_amdgcn_s_barrier()
#define LG0  asm volatile("s_waitcnt lgkmcnt(0)" ::: "memory")

// ---------------- router: fp64 logits/softmax for ordering robustness ----------------
__global__ __launch_bounds__(256) void k_router(
    const float* __restrict__ x, const float* __restrict__ gate_w,
    float* __restrict__ probs, int* __restrict__ topidx, float* __restrict__ topw)
{
  __shared__ float gwT[NEXP][DIM];
  int tid = threadIdx.x;
  for (int i = tid; i < DIM*NEXP; i += 256) gwT[i & 7][i >> 3] = gate_w[i];
  __syncthreads();
  int wave = tid >> 6, lane = tid & 63;
  int t = blockIdx.x * 4 + wave;
  const float* xr = x + (size_t)t * DIM;
  double acc[NEXP];
  #pragma unroll
  for (int e = 0; e < NEXP; e++) acc[e] = 0.0;
  for (int j = 0; j < DIM/64; j++){
    double xv = (double)xr[lane + 64*j];
    #pragma unroll
    for (int e = 0; e < NEXP; e++) acc[e] += xv * (double)gwT[e][lane + 64*j];
  }
  #pragma unroll
  for (int off = 32; off >= 1; off >>= 1){
    #pragma unroll
    for (int e = 0; e < NEXP; e++) acc[e] += __shfl_xor(acc[e], off, 64);
  }
  if (lane == 0){
    double m = acc[0];
    #pragma unroll
    for (int e = 1; e < NEXP; e++) m = fmax(m, acc[e]);
    double p[NEXP], Z = 0.0;
    #pragma unroll
    for (int e = 0; e < NEXP; e++){ p[e] = exp(acc[e] - m); Z += p[e]; }
    double invZ = 1.0 / Z;
    #pragma unroll
    for (int e = 0; e < NEXP; e++){ p[e] *= invZ; probs[t*NEXP + e] = (float)p[e]; }
    int i0 = 0; double p0 = p[0];
    #pragma unroll
    for (int e = 1; e < NEXP; e++) if (p[e] > p0){ p0 = p[e]; i0 = e; }
    int i1 = (i0 == 0) ? 1 : 0; double p1 = p[i1];
    #pragma unroll
    for (int e = 0; e < NEXP; e++) if (e != i0 && p[e] > p1){ p1 = p[e]; i1 = e; }
    double s = p0 + p1;
    topidx[t*2+0] = i0; topidx[t*2+1] = i1;
    topw [t*2+0] = (float)(p0/s); topw[t*2+1] = (float)(p1/s);
  }
}

// ---------------- ordered capacity scan ----------------
__global__ __launch_bounds__(1024) void k_scan(
    const int* __restrict__ topidx,
    int* __restrict__ slot_token, int* __restrict__ tok_slots,
    int* __restrict__ counts_total)
{
  __shared__ int sc[1024][NEXP];
  const int t = threadIdx.x;
  const int base_i = t * 32;
  int ids[32];
  #pragma unroll
  for (int j = 0; j < 32; j++) ids[j] = topidx[base_i + j];
  int b[NEXP];
  #pragma unroll
  for (int e = 0; e < NEXP; e++) b[e] = 0;
  #pragma unroll
  for (int j = 0; j < 32; j++){
    #pragma unroll
    for (int e = 0; e < NEXP; e++) if (ids[j] == e) b[e]++;
  }
  #pragma unroll
  for (int e = 0; e < NEXP; e++) sc[t][e] = b[e];
  __syncthreads();
  for (int off = 1; off < 1024; off <<= 1){
    int tmp[NEXP];
    #pragma unroll
    for (int e = 0; e < NEXP; e++) tmp[e] = (t >= off) ? sc[t-off][e] : 0;
    __syncthreads();
    #pragma unroll
    for (int e = 0; e < NEXP; e++) sc[t][e] += tmp[e];
    __syncthreads();
  }
  int myb[NEXP];
  #pragma unroll
  for (int e = 0; e < NEXP; e++) myb[e] = sc[t][e] - b[e];
  if (t == 1023){
    #pragma unroll
    for (int e = 0; e < NEXP; e++) counts_total[e] = sc[1023][e];
  }
  #pragma unroll
  for (int j = 0; j < 32; j++){
    int slot = -1;
    #pragma unroll
    for (int e = 0; e < NEXP; e++){
      if (ids[j] == e){
        int r = myb[e]; myb[e] = r + 1;
        if (r < CAP){
          slot = e*CAP + r;
          slot_token[slot] = (base_i + j) >> 1;
        }
      }
    }
    tok_slots[base_i + j] = slot;
  }
}

// ---------------- transpose + cast with row remap ----------------
// in [R][C] f32; out bf16 at out_row(c)*R + r.
// MODE 0: gate rows (c>>4)*32 + (c&15); MODE 1: up rows +16; MODE 2: plain c.
template<int MODE>
__global__ __launch_bounds__(256) void k_tc(
    const float* __restrict__ in, unsigned short* __restrict__ out,
    int R, int C, size_t estride)
{
  __shared__ float tile[64][65];
  const int e  = blockIdx.z;
  const float* ine = in + (size_t)e * R * C;
  unsigned short* oute = out + (size_t)e * estride;
  const int c0 = blockIdx.x * 64, r0 = blockIdx.y * 64;
  const int tx = threadIdx.x & 63, ty = threadIdx.x >> 6;
  #pragma unroll
  for (int i = 0; i < 16; i++){
    int r = ty*16 + i;
    tile[r][tx] = ine[(size_t)(r0 + r) * C + c0 + tx];
  }
  __syncthreads();
  #pragma unroll
  for (int i = 0; i < 16; i++){
    int c = c0 + ty*16 + i;
    int orow = (MODE == 0) ? ((c>>4)*32 + (c&15))
             : (MODE == 1) ? ((c>>4)*32 + 16 + (c&15))
             : c;
    oute[(size_t)orow * R + r0 + tx] = f2bf(tile[tx][ty*16 + i]);
  }
}

// ---------------- gather x rows into dispatched bf16 ----------------
__global__ __launch_bounds__(256) void k_gather(
    const float* __restrict__ x, const int* __restrict__ slot_token,
    unsigned short* __restrict__ disp)
{
  const int s = blockIdx.x;
  const int t = slot_token[s];
  const int tid = threadIdx.x;
  unsigned long long pk = 0ull;
  if (t >= 0){
    float4 v = *(const float4*)(x + (size_t)t*DIM + tid*4);
    pk =  (unsigned long long)f2bf(v.x)
       | ((unsigned long long)f2bf(v.y) << 16)
       | ((unsigned long long)f2bf(v.z) << 32)
       | ((unsigned long long)f2bf(v.w) << 48);
  }
  *(unsigned long long*)(disp + (size_t)s*DIM + tid*4) = pk;
}

// ================= 8-phase 256x256 GEMM core =================
// LDS: 2 bufs x {A-klo, A-khi, B-klo, B-khi} halves; half = 256 rows x 32 k (64B rows, swizzled)
__device__ __forceinline__ void stg(const unsigned short* gsrc, int ldg,
                                    unsigned short* Lh, int wave, int lane){
  const int sl = (lane & 3) ^ ((lane >> 3) & 3);       // inverse-swizzled source slot
  #pragma unroll
  for (int j = 0; j < 2; j++){
    int bi = wave*2 + j;
    gld16(gsrc + (size_t)(bi*16 + (lane >> 2))*ldg + sl*8, Lh + bi*512);
  }
}
__device__ __forceinline__ bf16x8 frd(const unsigned short* Lh, int r, int g){
  return *(const bf16x8*)(Lh + r*32 + (((g ^ ((r >> 1) & 3))) << 3));
}
template<int MG>
__device__ __forceinline__ void mm16(f32x4 (&acc)[8][4], const bf16x8 (&a)[4], const bf16x8 (&b)[4]){
  #pragma unroll
  for (int i = 0; i < 4; i++)
    #pragma unroll
    for (int n = 0; n < 4; n++)
      acc[MG*4+i][n] = __builtin_amdgcn_mfma_f32_16x16x32_bf16(a[i], b[n], acc[MG*4+i][n], 0, 0, 0);
}

// EPI 1: B' = interleaved gate/up [E][2*FF][KDIM]; out = hidden bf16 [E*CAP][FF], silu fused.
// EPI 2: B  = wdT [E][DIM][KDIM];  out = slot_out bf16 [E*CAP][DIM].
template<int KDIM, int EPI>
__global__ __launch_bounds__(512, 2) void k_gemm8(
    const unsigned short* __restrict__ A,
    const unsigned short* __restrict__ B,
    unsigned short* __restrict__ Out)
{
  constexpr int NT    = KDIM / 64;
  constexpr int BROWS = (EPI == 1) ? 2*FF : DIM;
  constexpr int LDO   = (EPI == 1) ? FF : DIM;
  __shared__ unsigned short lds[65536];     // 128 KiB
  const int e  = blockIdx.y;
  const int mt = blockIdx.x % 10, nt = blockIdx.x / 10;
  const int m0 = mt*256, n0 = nt*256;
  const unsigned short* Ab = A + ((size_t)e*CAP   + m0) * KDIM;
  const unsigned short* Bb = B + ((size_t)e*BROWS + n0) * KDIM;
  const int tid = threadIdx.x, wave = tid >> 6, lane = tid & 63;
  const int wr = wave >> 2, wc = wave & 3;          // 2M x 4N waves
  const int g = lane >> 4, l15 = lane & 15;

  f32x4 acc[8][4];
  const f32x4 z4 = {0.f,0.f,0.f,0.f};
  #pragma unroll
  for (int i = 0; i < 8; i++)
    #pragma unroll
    for (int n = 0; n < 4; n++) acc[i][n] = z4;

  // prologue: stage K-tile 0 (klo halves first)
  stg(Ab,      KDIM, lds + 0*8192, wave, lane);   // A klo
  stg(Bb,      KDIM, lds + 2*8192, wave, lane);   // B klo
  stg(Ab + 32, KDIM, lds + 1*8192, wave, lane);   // A khi
  stg(Bb + 32, KDIM, lds + 3*8192, wave, lane);   // B khi
  asm volatile("s_waitcnt vmcnt(4)" ::: "memory");  // klo landed
  SBAR; HBAR; SBAR;

  for (int kt = 0; kt < NT; ++kt){
    const int bsel = kt & 1;
    unsigned short* LA0 = lds + (bsel*4 + 0)*8192;
    unsigned short* LA1 = lds + (bsel*4 + 1)*8192;
    unsigned short* LB0 = lds + (bsel*4 + 2)*8192;
    unsigned short* LB1 = lds + (bsel*4 + 3)*8192;
    unsigned short* NA0 = lds + ((bsel^1)*4 + 0)*8192;
    unsigned short* NA1 = lds + ((bsel^1)*4 + 1)*8192;
    unsigned short* NB0 = lds + ((bsel^1)*4 + 2)*8192;
    unsigned short* NB1 = lds + ((bsel^1)*4 + 3)*8192;
    const bool st = (kt + 1 < NT);
    const unsigned short* An = Ab + (kt+1)*64;
    const unsigned short* Bn = Bb + (kt+1)*64;
    bf16x8 a[4], b[4];

    // ---- phase 0: klo, m-frags 0-3 ----
    #pragma unroll
    for (int i = 0; i < 4; i++) a[i] = frd(LA0, wr*128 + i*16 + l15, g);
    #pragma unroll
    for (int n = 0; n < 4; n++) b[n] = frd(LB0, wc*64 + n*16 + l15, g);
    if (st) stg(An, KDIM, NA0, wave, lane);
    SBAR; HBAR; LG0; SBAR;
    __builtin_amdgcn_s_setprio(1);  mm16<0>(acc, a, b);  __builtin_amdgcn_s_setprio(0);
    SBAR; HBAR; SBAR;

    // ---- phase 1: klo, m-frags 4-7 (reuse b) ----
    #pragma unroll
    for (int i = 0; i < 4; i++) a[i] = frd(LA0, wr*128 + (4+i)*16 + l15, g);
    if (st) stg(Bn, KDIM, NB0, wave, lane);
    SBAR; HBAR; LG0; SBAR;
    __builtin_amdgcn_s_setprio(1);  mm16<1>(acc, a, b);  __builtin_amdgcn_s_setprio(0);
    if (st) { asm volatile("s_waitcnt vmcnt(4)" ::: "memory"); }
    else    { asm volatile("s_waitcnt vmcnt(0)" ::: "memory"); }
    SBAR; HBAR; SBAR;

    // ---- phase 2: khi, m-frags 0-3 ----
    #pragma unroll
    for (int i = 0; i < 4; i++) a[i] = frd(LA1, wr*128 + i*16 + l15, g);
    #pragma unroll
    for (int n = 0; n < 4; n++) b[n] = frd(LB1, wc*64 + n*16 + l15, g);
    if (st) stg(An + 32, KDIM, NA1, wave, lane);
    SBAR; HBAR; LG0; SBAR;
    __builtin_amdgcn_s_setprio(1);  mm16<0>(acc, a, b);  __builtin_amdgcn_s_setprio(0);
    SBAR; HBAR; SBAR;

    // ---- phase 3: khi, m-frags 4-7 (reuse b) ----
    #pragma unroll
    for (int i = 0; i < 4; i++) a[i] = frd(LA1, wr*128 + (4+i)*16 + l15, g);
    if (st) stg(Bn + 32, KDIM, NB1, wave, lane);
    SBAR; HBAR; LG0; SBAR;
    __builtin_amdgcn_s_setprio(1);  mm16<1>(acc, a, b);  __builtin_amdgcn_s_setprio(0);
    if (st) { asm volatile("s_waitcnt vmcnt(4)" ::: "memory"); }
    SBAR; HBAR; SBAR;
  }

  // ---- epilogue ----
  if (EPI == 1){
    unsigned short* H = Out + ((size_t)e*CAP + m0 + wr*128) * (size_t)LDO;
    const int hc0 = (n0 + wc*64) >> 1;
    #pragma unroll
    for (int mf = 0; mf < 8; mf++)
      #pragma unroll
      for (int q = 0; q < 4; q++){
        int r = mf*16 + g*4 + q;
        #pragma unroll
        for (int p = 0; p < 2; p++){
          float gg = acc[mf][2*p][q], uu = acc[mf][2*p+1][q];
          float h = gg / (1.f + __expf(-gg)) * uu;
          H[(size_t)r*LDO + hc0 + p*16 + l15] = f2bf(h);
        }
      }
  } else {
    unsigned short* O = Out + ((size_t)e*CAP + m0 + wr*128) * (size_t)LDO + n0 + wc*64;
    #pragma unroll
    for (int mf = 0; mf < 8; mf++)
      #pragma unroll
      for (int q = 0; q < 4; q++){
        int r = mf*16 + g*4 + q;
        #pragma unroll
        for (int n = 0; n < 4; n++)
          O[(size_t)r*LDO + n*16 + l15] = f2bf(acc[mf][n][q]);
      }
  }
}

// ---------------- combine: out[t] = sum_k w_k * slot_out[slot_k(t)] ----------------
__global__ __launch_bounds__(128) void k_combine(
    const unsigned short* __restrict__ slot_out, const int* __restrict__ tok_slots,
    const float* __restrict__ topw, float* __restrict__ out)
{
  const int t = blockIdx.x, tid = threadIdx.x;
  const int s0 = tok_slots[t*2+0], s1 = tok_slots[t*2+1];
  const float w0 = topw[t*2+0], w1 = topw[t*2+1];
  float r[8];
  #pragma unroll
  for (int j = 0; j < 8; j++) r[j] = 0.f;
  if (s0 >= 0){
    bf16x8 v = *(const bf16x8*)(slot_out + (size_t)s0*DIM + tid*8);
    #pragma unroll
    for (int j = 0; j < 8; j++) r[j] += w0 * bf2f((unsigned short)v[j]);
  }
  if (s1 >= 0){
    bf16x8 v = *(const bf16x8*)(slot_out + (size_t)s1*DIM + tid*8);
    #pragma unroll
    for (int j = 0; j < 8; j++) r[j] += w1 * bf2f((unsigned short)v[j]);
  }
  float4* o = (float4*)(out + (size_t)t*DIM + tid*8);
  o[0] = make_float4(r[0], r[1], r[2], r[3]);
  o[1] = make_float4(r[4], r[5], r[6], r[7]);
}

// ---------------- aux loss ----------------
__global__ __launch_bounds__(256) void k_aux(
    const float* __restrict__ probs, const int* __restrict__ counts_total,
    float* __restrict__ aux_out)
{
  const int tid = threadIdx.x;
  float pe[NEXP];
  #pragma unroll
  for (int e = 0; e < NEXP; e++) pe[e] = 0.f;
  for (int i = tid; i < N_TOK; i += 256){
    #pragma unroll
    for (int e = 0; e < NEXP; e++) pe[e] += probs[i*NEXP + e];
  }
  #pragma unroll
  for (int off = 32; off >= 1; off >>= 1){
    #pragma unroll
    for (int e = 0; e < NEXP; e++) pe[e] += __shfl_xor(pe[e], off, 64);
  }
  __shared__ float part[4][NEXP];
  const int wave = tid >> 6, lane = tid & 63;
  if (lane == 0){
    #pragma unroll
    for (int e = 0; e < NEXP; e++) part[wave][e] = pe[e];
  }
  __syncthreads();
  if (tid == 0){
    float aux = 0.f;
    for (int e = 0; e < NEXP; e++){
      float P = (part[0][e] + part[1][e] + part[2][e] + part[3][e]) / (float)N_TOK;
      float f = (float)counts_total[e] / ((float)(N_TOK*2) + 1e-9f);
      aux += f * P;
    }
    aux_out[0] = (float)NEXP * aux * 0.01f;
  }
}

extern "C" void kernel_launch(void* const* d_in, const int* in_sizes, int n_in,
                              void* d_out, int out_size, void* d_ws, size_t ws_size,
                              hipStream_t stream)
{
  const float* x      = (const float*)d_in[0];
  const float* gate_w = (const float*)d_in[1];
  const float* w_gate = (const float*)d_in[2];
  const float* w_up   = (const float*)d_in[3];
  const float* w_down = (const float*)d_in[4];
  float* out = (float*)d_out;

  uint8_t* ws = (uint8_t*)d_ws;
  float* probs        = (float*)ws;             ws += (size_t)N_TOK*NEXP*4;
  int*   topidx       = (int*)ws;               ws += (size_t)N_TOK*2*4;
  float* topw         = (float*)ws;             ws += (size_t)N_TOK*2*4;
  int*   slot_token   = (int*)ws;               ws += (size_t)NSLOT*4;
  int*   tok_slots    = (int*)ws;               ws += (size_t)N_TOK*2*4;
  int*   counts_total = (int*)ws;               ws += 256;
  unsigned short* disp   = (unsigned short*)ws; ws += (size_t)NSLOT*DIM*2;     // aliased as slot_out after GEMM1
  unsigned short* hidden = (unsigned short*)ws; ws += (size_t)NSLOT*FF*2;
  unsigned short* B1     = (unsigned short*)ws; ws += (size_t)NEXP*2*FF*DIM*2; // interleaved gate/up
  unsigned short* wdT    = (unsigned short*)ws; ws += (size_t)NEXP*DIM*FF*2;
  size_t need = (size_t)(ws - (uint8_t*)d_ws);
  if (ws_size < need) return;
  unsigned short* slot_out = disp;

  hipMemsetAsync(slot_token, 0xFF, (size_t)NSLOT * sizeof(int), stream);

  k_router<<<N_TOK/4, 256, 0, stream>>>(x, gate_w, probs, topidx, topw);
  k_scan<<<1, 1024, 0, stream>>>(topidx, slot_token, tok_slots, counts_total);
  k_tc<0><<<dim3(FF/64, DIM/64, NEXP), 256, 0, stream>>>(w_gate, B1, DIM, FF, (size_t)2*FF*DIM);
  k_tc<1><<<dim3(FF/64, DIM/64, NEXP), 256, 0, stream>>>(w_up,   B1, DIM, FF, (size_t)2*FF*DIM);
  k_tc<2><<<dim3(DIM/64, FF/64, NEXP), 256, 0, stream>>>(w_down, wdT, FF, DIM, (size_t)DIM*FF);
  k_gather<<<NSLOT, 256, 0, stream>>>(x, slot_token, disp);
  k_gemm8<DIM, 1><<<dim3(160, NEXP), 512, 0, stream>>>(disp, B1, hidden);
  k_gemm8<FF, 2><<<dim3(40, NEXP), 512, 0, stream>>>(hidden, wdT, slot_out);
  k_combine<<<N_TOK, 128, 0, stream>>>(slot_out, tok_slots, topw, out);
  k_aux<<<1, 256, 0, stream>>>(probs, counts_total, out + (size_t)N_TOK*DIM);
}

// Round 3
// 506.541 us; speedup vs baseline: 1.5288x; 1.0494x over previous
//
#include <hip/hip_runtime.h>
#include <stdint.h>

#define N_TOK 16384
#define DIM   1024
#define NEXP  8
#define FF    2048
#define CAP   2560
#define NSLOT (NEXP*CAP)   // 20480

using f32x4  = __attribute__((ext_vector_type(4))) float;
using bf16x8 = __attribute__((ext_vector_type(8))) short;

__device__ __forceinline__ unsigned short f2bf(float f){
  union { float f; unsigned u; } c; c.f = f;
  unsigned u = c.u + 0x7FFFu + ((c.u >> 16) & 1u);   // RNE
  return (unsigned short)(u >> 16);
}
__device__ __forceinline__ float bf2f(unsigned short h){
  union { unsigned u; float f; } c; c.u = ((unsigned)h) << 16; return c.f;
}

__device__ __forceinline__ void gld16(const unsigned short* g, unsigned short* l){
  __builtin_amdgcn_global_load_lds((__attribute__((address_space(1))) void*)(void*)g,
                                   (__attribute__((address_space(3))) void*)l,
                                   16, 0, 0);
}

#define SBAR __builtin_amdgcn_sched_barrier(0)
#define HBAR __builtin_amdgcn_s_barrier()
#define LG0  asm volatile("s_waitcnt lgkmcnt(0)" ::: "memory")

// ---------------- router: fp64 logits/softmax for ordering robustness ----------------
__global__ __launch_bounds__(256) void k_router(
    const float* __restrict__ x, const float* __restrict__ gate_w,
    float* __restrict__ probs, int* __restrict__ topidx, float* __restrict__ topw)
{
  __shared__ float gwT[NEXP][DIM];
  int tid = threadIdx.x;
  for (int i = tid; i < DIM*NEXP; i += 256) gwT[i & 7][i >> 3] = gate_w[i];
  __syncthreads();
  int wave = tid >> 6, lane = tid & 63;
  int t = blockIdx.x * 4 + wave;
  const float* xr = x + (size_t)t * DIM;
  double acc[NEXP];
  #pragma unroll
  for (int e = 0; e < NEXP; e++) acc[e] = 0.0;
  for (int j = 0; j < DIM/64; j++){
    double xv = (double)xr[lane + 64*j];
    #pragma unroll
    for (int e = 0; e < NEXP; e++) acc[e] += xv * (double)gwT[e][lane + 64*j];
  }
  #pragma unroll
  for (int off = 32; off >= 1; off >>= 1){
    #pragma unroll
    for (int e = 0; e < NEXP; e++) acc[e] += __shfl_xor(acc[e], off, 64);
  }
  if (lane == 0){
    double m = acc[0];
    #pragma unroll
    for (int e = 1; e < NEXP; e++) m = fmax(m, acc[e]);
    double p[NEXP], Z = 0.0;
    #pragma unroll
    for (int e = 0; e < NEXP; e++){ p[e] = exp(acc[e] - m); Z += p[e]; }
    double invZ = 1.0 / Z;
    #pragma unroll
    for (int e = 0; e < NEXP; e++){ p[e] *= invZ; probs[t*NEXP + e] = (float)p[e]; }
    int i0 = 0; double p0 = p[0];
    #pragma unroll
    for (int e = 1; e < NEXP; e++) if (p[e] > p0){ p0 = p[e]; i0 = e; }
    int i1 = (i0 == 0) ? 1 : 0; double p1 = p[i1];
    #pragma unroll
    for (int e = 0; e < NEXP; e++) if (e != i0 && p[e] > p1){ p1 = p[e]; i1 = e; }
    double s = p0 + p1;
    topidx[t*2+0] = i0; topidx[t*2+1] = i1;
    topw [t*2+0] = (float)(p0/s); topw[t*2+1] = (float)(p1/s);
  }
}

// ---------------- ordered capacity scan ----------------
__global__ __launch_bounds__(1024) void k_scan(
    const int* __restrict__ topidx,
    int* __restrict__ slot_token, int* __restrict__ tok_slots,
    int* __restrict__ counts_total)
{
  __shared__ int sc[1024][NEXP];
  const int t = threadIdx.x;
  const int base_i = t * 32;
  int ids[32];
  #pragma unroll
  for (int j = 0; j < 32; j++) ids[j] = topidx[base_i + j];
  int b[NEXP];
  #pragma unroll
  for (int e = 0; e < NEXP; e++) b[e] = 0;
  #pragma unroll
  for (int j = 0; j < 32; j++){
    #pragma unroll
    for (int e = 0; e < NEXP; e++) if (ids[j] == e) b[e]++;
  }
  #pragma unroll
  for (int e = 0; e < NEXP; e++) sc[t][e] = b[e];
  __syncthreads();
  for (int off = 1; off < 1024; off <<= 1){
    int tmp[NEXP];
    #pragma unroll
    for (int e = 0; e < NEXP; e++) tmp[e] = (t >= off) ? sc[t-off][e] : 0;
    __syncthreads();
    #pragma unroll
    for (int e = 0; e < NEXP; e++) sc[t][e] += tmp[e];
    __syncthreads();
  }
  int myb[NEXP];
  #pragma unroll
  for (int e = 0; e < NEXP; e++) myb[e] = sc[t][e] - b[e];
  if (t == 1023){
    #pragma unroll
    for (int e = 0; e < NEXP; e++) counts_total[e] = sc[1023][e];
  }
  #pragma unroll
  for (int j = 0; j < 32; j++){
    int slot = -1;
    #pragma unroll
    for (int e = 0; e < NEXP; e++){
      if (ids[j] == e){
        int r = myb[e]; myb[e] = r + 1;
        if (r < CAP){
          slot = e*CAP + r;
          slot_token[slot] = (base_i + j) >> 1;
        }
      }
    }
    tok_slots[base_i + j] = slot;
  }
}

// ---------------- transpose + cast with row remap ----------------
template<int MODE>
__global__ __launch_bounds__(256) void k_tc(
    const float* __restrict__ in, unsigned short* __restrict__ out,
    int R, int C, size_t estride)
{
  __shared__ float tile[64][65];
  const int e  = blockIdx.z;
  const float* ine = in + (size_t)e * R * C;
  unsigned short* oute = out + (size_t)e * estride;
  const int c0 = blockIdx.x * 64, r0 = blockIdx.y * 64;
  const int tx = threadIdx.x & 63, ty = threadIdx.x >> 6;
  #pragma unroll
  for (int i = 0; i < 16; i++){
    int r = ty*16 + i;
    tile[r][tx] = ine[(size_t)(r0 + r) * C + c0 + tx];
  }
  __syncthreads();
  #pragma unroll
  for (int i = 0; i < 16; i++){
    int c = c0 + ty*16 + i;
    int orow = (MODE == 0) ? ((c>>4)*32 + (c&15))
             : (MODE == 1) ? ((c>>4)*32 + 16 + (c&15))
             : c;
    oute[(size_t)orow * R + r0 + tx] = f2bf(tile[tx][ty*16 + i]);
  }
}

// ---------------- gather x rows into dispatched bf16 ----------------
__global__ __launch_bounds__(256) void k_gather(
    const float* __restrict__ x, const int* __restrict__ slot_token,
    unsigned short* __restrict__ disp)
{
  const int s = blockIdx.x;
  const int t = slot_token[s];
  const int tid = threadIdx.x;
  unsigned long long pk = 0ull;
  if (t >= 0){
    float4 v = *(const float4*)(x + (size_t)t*DIM + tid*4);
    pk =  (unsigned long long)f2bf(v.x)
       | ((unsigned long long)f2bf(v.y) << 16)
       | ((unsigned long long)f2bf(v.z) << 32)
       | ((unsigned long long)f2bf(v.w) << 48);
  }
  *(unsigned long long*)(disp + (size_t)s*DIM + tid*4) = pk;
}

// ================= ring-4 half-K 256x256 GEMM core =================
// half-slot = 32 KiB: A(256r x 32k) at +0, B(256r x 32k) at +8192 shorts.
// Half h staged during half h-3 (A in phase A, B in phase B) -> 6-phase lead.
__device__ __forceinline__ void stg(const unsigned short* gsrc, int ldg,
                                    unsigned short* Lh, int wave, int lane){
  const int sl = (lane & 3) ^ ((lane >> 3) & 3);   // inverse-swizzled source slot
  #pragma unroll
  for (int j = 0; j < 2; j++){
    int bi = wave*2 + j;
    gld16(gsrc + (size_t)(bi*16 + (lane >> 2))*ldg + sl*8, Lh + bi*512);
  }
}
__device__ __forceinline__ bf16x8 frd(const unsigned short* Lh, int r, int g){
  return *(const bf16x8*)(Lh + r*32 + (((g ^ ((r >> 1) & 3))) << 3));
}
template<int MG>
__device__ __forceinline__ void mm16(f32x4 (&acc)[8][4], const bf16x8 (&a)[4], const bf16x8 (&b)[4]){
  #pragma unroll
  for (int i = 0; i < 4; i++)
    #pragma unroll
    for (int n = 0; n < 4; n++)
      acc[MG*4+i][n] = __builtin_amdgcn_mfma_f32_16x16x32_bf16(a[i], b[n], acc[MG*4+i][n], 0, 0, 0);
}

// One half: 2 phases x 16 MFMA. RS = ring slot (compile-time), DOSTG stage h+3,
// VMW = end-of-half vmcnt (-1 = none). b[] persists phase A -> B.
#define HALF_STEP(RS, DOSTG, VMW, ASRC, BSRC)                                   \
  {                                                                             \
    unsigned short* LA = lds + (RS)*16384;                                      \
    unsigned short* LB = LA + 8192;                                             \
    unsigned short* NS = lds + (((RS)+3)&3)*16384;                              \
    bf16x8 a[4], b[4];                                                          \
    _Pragma("unroll")                                                           \
    for (int i = 0; i < 4; i++) a[i] = frd(LA, wr*128 + i*16 + l15, g);         \
    _Pragma("unroll")                                                           \
    for (int n = 0; n < 4; n++) b[n] = frd(LB, wc*64 + n*16 + l15, g);          \
    if (DOSTG) stg(ASRC, KDIM, NS, wave, lane);                                 \
    SBAR; HBAR; LG0; SBAR;                                                      \
    __builtin_amdgcn_s_setprio(1);  mm16<0>(acc, a, b);                         \
    __builtin_amdgcn_s_setprio(0);                                              \
    SBAR; HBAR; SBAR;                                                           \
    _Pragma("unroll")                                                           \
    for (int i = 0; i < 4; i++) a[i] = frd(LA, wr*128 + (4+i)*16 + l15, g);     \
    if (DOSTG) stg(BSRC, KDIM, NS + 8192, wave, lane);                          \
    SBAR; HBAR; LG0; SBAR;                                                      \
    __builtin_amdgcn_s_setprio(1);  mm16<1>(acc, a, b);                         \
    __builtin_amdgcn_s_setprio(0);                                              \
    if ((VMW) == 8) { asm volatile("s_waitcnt vmcnt(8)" ::: "memory"); }        \
    else if ((VMW) == 4) { asm volatile("s_waitcnt vmcnt(4)" ::: "memory"); }   \
    else if ((VMW) == 0) { asm volatile("s_waitcnt vmcnt(0)" ::: "memory"); }   \
    SBAR; HBAR; SBAR;                                                           \
  }

// EPI 1: B' = interleaved gate/up [E][2*FF][KDIM]; out = hidden bf16, silu fused.
// EPI 2: B  = wdT [E][DIM][KDIM];  out = slot_out bf16 [E*CAP][DIM].
template<int KDIM, int EPI>
__global__ __launch_bounds__(512, 2) void k_gemm8(
    const unsigned short* __restrict__ A,
    const unsigned short* __restrict__ B,
    unsigned short* __restrict__ Out)
{
  constexpr int NH    = KDIM / 32;               // halves (32 or 64, %4==0)
  constexpr int BROWS = (EPI == 1) ? 2*FF : DIM;
  constexpr int LDO   = (EPI == 1) ? FF : DIM;
  __shared__ unsigned short lds[65536];          // 128 KiB = 4 half-slots
  const int id = blockIdx.x;
  const int e  = id & 7;                          // XCD-chunked: expert per XCD
  const int t  = id >> 3;
  const int mt = t % 10, nt = t / 10;
  const int m0 = mt*256, n0 = nt*256;
  const unsigned short* Ab = A + ((size_t)e*CAP   + m0) * KDIM;
  const unsigned short* Bb = B + ((size_t)e*BROWS + n0) * KDIM;
  const int tid = threadIdx.x, wave = tid >> 6, lane = tid & 63;
  const int wr = wave >> 2, wc = wave & 3;        // 2M x 4N waves
  const int g = lane >> 4, l15 = lane & 15;

  f32x4 acc[8][4];
  const f32x4 z4 = {0.f,0.f,0.f,0.f};
  #pragma unroll
  for (int i = 0; i < 8; i++)
    #pragma unroll
    for (int n = 0; n < 4; n++) acc[i][n] = z4;

  // prologue: stage halves 0,1,2 (12 loads/thread); wait half 0 (<=8 left)
  stg(Ab,      KDIM, lds + 0*16384,        wave, lane);
  stg(Bb,      KDIM, lds + 0*16384 + 8192, wave, lane);
  stg(Ab + 32, KDIM, lds + 1*16384,        wave, lane);
  stg(Bb + 32, KDIM, lds + 1*16384 + 8192, wave, lane);
  stg(Ab + 64, KDIM, lds + 2*16384,        wave, lane);
  stg(Bb + 64, KDIM, lds + 2*16384 + 8192, wave, lane);
  asm volatile("s_waitcnt vmcnt(8)" ::: "memory");
  SBAR; HBAR; SBAR;

  // steady: halves 0..NH-5 (stage h+3, vmcnt(8) -> h+1 landed)
  for (int h = 0; h + 8 <= NH; h += 4){
    HALF_STEP(0, true, 8, Ab + (size_t)(h+3)*32, Bb + (size_t)(h+3)*32);
    HALF_STEP(1, true, 8, Ab + (size_t)(h+4)*32, Bb + (size_t)(h+4)*32);
    HALF_STEP(2, true, 8, Ab + (size_t)(h+5)*32, Bb + (size_t)(h+5)*32);
    HALF_STEP(3, true, 8, Ab + (size_t)(h+6)*32, Bb + (size_t)(h+6)*32);
  }
  // tail: halves NH-4..NH-1 (slots 0..3); stage NH-1; drain 8/4/0/none
  HALF_STEP(0, true,  8, Ab + (size_t)(NH-1)*32, Bb + (size_t)(NH-1)*32);
  HALF_STEP(1, false, 4, Ab, Bb);
  HALF_STEP(2, false, 0, Ab, Bb);
  HALF_STEP(3, false, -1, Ab, Bb);

  // ---- epilogue ----
  if (EPI == 1){
    unsigned short* H = Out + ((size_t)e*CAP + m0 + wr*128) * (size_t)LDO;
    const int hc0 = (n0 + wc*64) >> 1;
    #pragma unroll
    for (int mf = 0; mf < 8; mf++)
      #pragma unroll
      for (int q = 0; q < 4; q++){
        int r = mf*16 + g*4 + q;
        #pragma unroll
        for (int p = 0; p < 2; p++){
          float gg = acc[mf][2*p][q], uu = acc[mf][2*p+1][q];
          float h = gg / (1.f + __expf(-gg)) * uu;
          H[(size_t)r*LDO + hc0 + p*16 + l15] = f2bf(h);
        }
      }
  } else {
    unsigned short* O = Out + ((size_t)e*CAP + m0 + wr*128) * (size_t)LDO + n0 + wc*64;
    #pragma unroll
    for (int mf = 0; mf < 8; mf++)
      #pragma unroll
      for (int q = 0; q < 4; q++){
        int r = mf*16 + g*4 + q;
        #pragma unroll
        for (int n = 0; n < 4; n++)
          O[(size_t)r*LDO + n*16 + l15] = f2bf(acc[mf][n][q]);
      }
  }
}

// ---------------- combine: out[t] = sum_k w_k * slot_out[slot_k(t)] ----------------
__global__ __launch_bounds__(128) void k_combine(
    const unsigned short* __restrict__ slot_out, const int* __restrict__ tok_slots,
    const float* __restrict__ topw, float* __restrict__ out)
{
  const int t = blockIdx.x, tid = threadIdx.x;
  const int s0 = tok_slots[t*2+0], s1 = tok_slots[t*2+1];
  const float w0 = topw[t*2+0], w1 = topw[t*2+1];
  float r[8];
  #pragma unroll
  for (int j = 0; j < 8; j++) r[j] = 0.f;
  if (s0 >= 0){
    bf16x8 v = *(const bf16x8*)(slot_out + (size_t)s0*DIM + tid*8);
    #pragma unroll
    for (int j = 0; j < 8; j++) r[j] += w0 * bf2f((unsigned short)v[j]);
  }
  if (s1 >= 0){
    bf16x8 v = *(const bf16x8*)(slot_out + (size_t)s1*DIM + tid*8);
    #pragma unroll
    for (int j = 0; j < 8; j++) r[j] += w1 * bf2f((unsigned short)v[j]);
  }
  float4* o = (float4*)(out + (size_t)t*DIM + tid*8);
  o[0] = make_float4(r[0], r[1], r[2], r[3]);
  o[1] = make_float4(r[4], r[5], r[6], r[7]);
}

// ---------------- aux loss ----------------
__global__ __launch_bounds__(256) void k_aux(
    const float* __restrict__ probs, const int* __restrict__ counts_total,
    float* __restrict__ aux_out)
{
  const int tid = threadIdx.x;
  float pe[NEXP];
  #pragma unroll
  for (int e = 0; e < NEXP; e++) pe[e] = 0.f;
  for (int i = tid; i < N_TOK; i += 256){
    #pragma unroll
    for (int e = 0; e < NEXP; e++) pe[e] += probs[i*NEXP + e];
  }
  #pragma unroll
  for (int off = 32; off >= 1; off >>= 1){
    #pragma unroll
    for (int e = 0; e < NEXP; e++) pe[e] += __shfl_xor(pe[e], off, 64);
  }
  __shared__ float part[4][NEXP];
  const int wave = tid >> 6, lane = tid & 63;
  if (lane == 0){
    #pragma unroll
    for (int e = 0; e < NEXP; e++) part[wave][e] = pe[e];
  }
  __syncthreads();
  if (tid == 0){
    float aux = 0.f;
    for (int e = 0; e < NEXP; e++){
      float P = (part[0][e] + part[1][e] + part[2][e] + part[3][e]) / (float)N_TOK;
      float f = (float)counts_total[e] / ((float)(N_TOK*2) + 1e-9f);
      aux += f * P;
    }
    aux_out[0] = (float)NEXP * aux * 0.01f;
  }
}

extern "C" void kernel_launch(void* const* d_in, const int* in_sizes, int n_in,
                              void* d_out, int out_size, void* d_ws, size_t ws_size,
                              hipStream_t stream)
{
  const float* x      = (const float*)d_in[0];
  const float* gate_w = (const float*)d_in[1];
  const float* w_gate = (const float*)d_in[2];
  const float* w_up   = (const float*)d_in[3];
  const float* w_down = (const float*)d_in[4];
  float* out = (float*)d_out;

  uint8_t* ws = (uint8_t*)d_ws;
  float* probs        = (float*)ws;             ws += (size_t)N_TOK*NEXP*4;
  int*   topidx       = (int*)ws;               ws += (size_t)N_TOK*2*4;
  float* topw         = (float*)ws;             ws += (size_t)N_TOK*2*4;
  int*   slot_token   = (int*)ws;               ws += (size_t)NSLOT*4;
  int*   tok_slots    = (int*)ws;               ws += (size_t)N_TOK*2*4;
  int*   counts_total = (int*)ws;               ws += 256;
  unsigned short* disp   = (unsigned short*)ws; ws += (size_t)NSLOT*DIM*2;     // aliased as slot_out after GEMM1
  unsigned short* hidden = (unsigned short*)ws; ws += (size_t)NSLOT*FF*2;
  unsigned short* B1     = (unsigned short*)ws; ws += (size_t)NEXP*2*FF*DIM*2; // interleaved gate/up
  unsigned short* wdT    = (unsigned short*)ws; ws += (size_t)NEXP*DIM*FF*2;
  size_t need = (size_t)(ws - (uint8_t*)d_ws);
  if (ws_size < need) return;
  unsigned short* slot_out = disp;

  hipMemsetAsync(slot_token, 0xFF, (size_t)NSLOT * sizeof(int), stream);

  k_router<<<N_TOK/4, 256, 0, stream>>>(x, gate_w, probs, topidx, topw);
  k_scan<<<1, 1024, 0, stream>>>(topidx, slot_token, tok_slots, counts_total);
  k_tc<0><<<dim3(FF/64, DIM/64, NEXP), 256, 0, stream>>>(w_gate, B1, DIM, FF, (size_t)2*FF*DIM);
  k_tc<1><<<dim3(FF/64, DIM/64, NEXP), 256, 0, stream>>>(w_up,   B1, DIM, FF, (size_t)2*FF*DIM);
  k_tc<2><<<dim3(DIM/64, FF/64, NEXP), 256, 0, stream>>>(w_down, wdT, FF, DIM, (size_t)DIM*FF);
  k_gather<<<NSLOT, 256, 0, stream>>>(x, slot_token, disp);
  k_gemm8<DIM, 1><<<1280, 512, 0, stream>>>(disp, B1, hidden);
  k_gemm8<FF, 2><<<320, 512, 0, stream>>>(hidden, wdT, slot_out);
  k_combine<<<N_TOK, 128, 0, stream>>>(slot_out, tok_slots, topw, out);
  k_aux<<<1, 256, 0, stream>>>(probs, counts_total, out + (size_t)N_TOK*DIM);
}